// Round 1
// 349.596 us; speedup vs baseline: 1.0063x; 1.0063x over previous
//
#include <hip/hip_runtime.h>
#include <math.h>

#define TOK 8192   // B*S tokens
#define HD  512    // hidden
#define NE  8      // experts
#define DFF 2048   // ffn dim

// ---------- bf16 helpers ----------
typedef __attribute__((ext_vector_type(8))) short bf16x8;
typedef __attribute__((ext_vector_type(4))) float floatx4;

__device__ inline unsigned short f2bf(float f) {
    union { float f; unsigned u; } v; v.f = f;
    unsigned r = v.u + 0x7FFFu + ((v.u >> 16) & 1u);   // round-nearest-even
    return (unsigned short)(r >> 16);
}

__device__ inline float gelu_exact(float v) {
    return 0.5f * v * (1.f + erff(v * 0.70710678118654752f));
}

// ---------- async global->LDS (16 B/lane; LDS dst = wave-uniform base + lane*16) ----------
typedef __attribute__((address_space(1))) const unsigned int glb_u32;
typedef __attribute__((address_space(3))) unsigned int lds_u32;
__device__ __forceinline__ void gload16(const unsigned short* g, unsigned short* l) {
    __builtin_amdgcn_global_load_lds((glb_u32*)g, (lds_u32*)l, 16, 0, 0);
}

// ---------------- prep kernel: gate (32 blocks) + weight transpose (4096 blocks) ----------------
// Independent inputs -> fused into one launch so they run concurrently.
__global__ __launch_bounds__(256) void prep_kernel(
    const float* __restrict__ x, const float* __restrict__ gW, const float* __restrict__ gb,
    const float* __restrict__ W1, const float* __restrict__ W2,
    int* __restrict__ seg_count, float* __restrict__ probs_sum,
    int* __restrict__ seg_token, float* __restrict__ seg_w,
    unsigned short* __restrict__ xb,
    unsigned short* __restrict__ W1t, unsigned short* __restrict__ W2t)
{
    __shared__ __align__(16) char shraw[16896];
    int bid = blockIdx.x;
    int tid = threadIdx.x;

    if (bid >= 32) {
        // ---- transpose block: z<NE: W1 [e][HD][DFF]->W1t [e][DFF][HD]; else W2 -> W2t
        int b = bid - 32;
        float (*tile)[65] = (float(*)[65])shraw;
        int z = b >> 8, rem = b & 255;
        int xq = rem & 31, yq = rem >> 5;
        const float* src; unsigned short* dst; int C, R, cb, rb;
        if (z < NE) {
            src = W1 + (size_t)z * HD * DFF; dst = W1t + (size_t)z * HD * DFF;
            R = HD; C = DFF; cb = xq; rb = yq;
        } else {
            int e = z - NE;
            src = W2 + (size_t)e * DFF * HD; dst = W2t + (size_t)e * DFF * HD;
            R = DFF; C = HD; cb = yq; rb = xq;
        }
        int c0 = cb * 64, r0 = rb * 64;
        int lc = tid & 63, lrw = tid >> 6;
        #pragma unroll
        for (int rr = lrw; rr < 64; rr += 4)
            tile[rr][lc] = src[(size_t)(r0 + rr) * C + c0 + lc];
        __syncthreads();
        #pragma unroll
        for (int cc = lrw; cc < 64; cc += 4)
            dst[(size_t)(c0 + cc) * R + r0 + lc] = f2bf(tile[lc][cc]);
        return;
    }

    // ---- gate block (fp32 exact) + fused x->bf16 conversion
    float* sW    = (float*)shraw;             // 16384 B
    float* psum  = (float*)(shraw + 16384);   // 32 B
    int*   lcount = (int*)(shraw + 16448);
    int*   lbase  = (int*)(shraw + 16512);

    for (int i = tid; i < HD * NE; i += 256) sW[i] = gW[i];
    if (tid < NE) { psum[tid] = 0.f; lcount[tid] = 0; }
    __syncthreads();

    int t = bid * 256 + tid;
    float logit[NE];
    #pragma unroll
    for (int e = 0; e < NE; e++) logit[e] = gb[e];

    const float4* xr4 = reinterpret_cast<const float4*>(x + (size_t)t * HD);
    ushort4* xbw = reinterpret_cast<ushort4*>(xb + (size_t)t * HD);
    for (int j4 = 0; j4 < HD / 4; j4++) {
        float4 xv = xr4[j4];
        int j = j4 * 4;
        ushort4 o; o.x = f2bf(xv.x); o.y = f2bf(xv.y); o.z = f2bf(xv.z); o.w = f2bf(xv.w);
        xbw[j4] = o;
        #pragma unroll
        for (int e = 0; e < NE; e++) {
            logit[e] += xv.x * sW[(j + 0) * NE + e] + xv.y * sW[(j + 1) * NE + e]
                      + xv.z * sW[(j + 2) * NE + e] + xv.w * sW[(j + 3) * NE + e];
        }
    }

    float mx = logit[0];
    #pragma unroll
    for (int e = 1; e < NE; e++) mx = fmaxf(mx, logit[e]);
    float pe[NE]; float s = 0.f;
    #pragma unroll
    for (int e = 0; e < NE; e++) { pe[e] = expf(logit[e] - mx); s += pe[e]; }
    float inv = 1.f / s;
    int l = tid & 63;
    #pragma unroll
    for (int e = 0; e < NE; e++) {          // wave-shuffle reduce, 1 LDS atomic/wave/e
        float v = pe[e] * inv;
        for (int off = 32; off; off >>= 1) v += __shfl_down(v, off);
        if (l == 0) atomicAdd(&psum[e], v);
    }

    // top-2, lowest-index tie break (matches jax.lax.top_k)
    int i0 = 0; float v0 = logit[0];
    #pragma unroll
    for (int e = 1; e < NE; e++) if (logit[e] > v0) { v0 = logit[e]; i0 = e; }
    int i1 = -1; float v1 = -3.4e38f;
    #pragma unroll
    for (int e = 0; e < NE; e++) if (e != i0 && logit[e] > v1) { v1 = logit[e]; i1 = e; }
    float e1 = expf(v1 - v0);
    float w0 = 1.f / (1.f + e1);
    float w1 = e1 / (1.f + e1);

    int r0 = atomicAdd(&lcount[i0], 1);
    int r1 = atomicAdd(&lcount[i1], 1);
    __syncthreads();
    if (tid < NE) lbase[tid] = atomicAdd(&seg_count[tid], lcount[tid]);
    __syncthreads();
    int p0 = lbase[i0] + r0;
    seg_token[i0 * TOK + p0] = t; seg_w[i0 * TOK + p0] = w0;
    int p1 = lbase[i1] + r1;
    seg_token[i1 * TOK + p1] = t; seg_w[i1 * TOK + p1] = w1;

    __syncthreads();
    if (tid < NE) atomicAdd(&probs_sum[tid], psum[tid]);
}

// ---------------- split GEMM path: triple-buffered counted-vmcnt pipeline ----------------
// 128x128 tiles, BK=32, 4 waves x 64x64. 3 LDS buffers (49 KB -> 3 blocks/CU vs old 2).
// Per iter: s_waitcnt vmcnt(4) [buf k landed; buf k+1 stays in flight] -> s_barrier ->
// issue DMA(k+2) -> ds_read 8 frags -> 16 MFMA. Never drains vmcnt to 0 in the loop
// (m201/T3+T4 pattern). BK=32 rows are 64 B so frag ds_read_b128 is bank-balanced
// (bank = 16*(row&1)+4*chunk+word -> 8 accesses/bank = floor); no swizzle needed,
// and the DMA source is linear per row (4 lanes x 16 B = full 64 B line).
#define TM  128
#define TN  128
#define BK  32

// GEMM1: hbuf[row, n] = gelu( xb[seg_token[e][row], :] @ W1t[e][n, :] + b1[e][n] )
// Also: block 0 computes l_aux + expert_counts (folded finalize).
__global__ __launch_bounds__(256) void gemm1_kernel(
    const unsigned short* __restrict__ xb,
    const unsigned short* __restrict__ W1t,   // [E][DFF][HD] n-major
    const float* __restrict__ bias1,
    const int* __restrict__ seg_count, const float* __restrict__ probs_sum,
    const int* __restrict__ seg_token,
    unsigned short* __restrict__ hbuf,        // [rows][DFF]
    float* __restrict__ out_tail)
{
    int bid = blockIdx.x;
    int tid = threadIdx.x;

    if (bid == 0) {           // folded finalize
        if (tid < NE) out_tail[1 + tid] = (float)seg_count[tid];
        else if (tid == 64) {
            float s = 0.f;
            #pragma unroll
            for (int e2 = 0; e2 < NE; e2++) {
                float p = probs_sum[e2] * (1.f / (float)TOK);
                s += p * p;
            }
            out_tail[0] = s * (float)NE;
        }
    }

    int e  = bid & 7;                          // low bits -> XCD affinity
    int r2 = bid >> 3;
    int nb = r2 & 15;                          // DFF/TN = 16
    int mb = r2 >> 4;                          // 0..63
    int cnt = seg_count[e];
    if (mb * TM >= cnt) return;
    int off_e = 0;
    #pragma unroll
    for (int ee = 0; ee < NE; ee++) if (ee < e) off_e += (seg_count[ee] + 127) & ~127;
    int hb = off_e + mb * TM;

    __shared__ __align__(16) unsigned short smem[3][2][TM * BK];   // 49152 B
    __shared__ int tok_s[TM];
    if (tid < TM) {
        int gi = mb * TM + tid;
        tok_s[tid] = seg_token[e * TOK + ((gi < cnt) ? gi : 0)];   // pad: dup row0
    }
    __syncthreads();

    int w = tid >> 6, l = tid & 63;
    int lr = l & 15, crow = (l >> 4) * 4;
    int wm = (w & 1) * 64, wn = (w >> 1) * 64;
    int kq = (l >> 4) * 8;                     // frag k-chunk (8 bf16 = 16 B)
    const unsigned short* w1e = W1t + (size_t)e * DFF * HD + (size_t)(nb * TN) * HD;

    // staging: wave w stages rows [w*32, w*32+32) -> 2 gload16 per operand.
    // lane l covers row +(l>>2), 16B slot (l&3); linear both sides.
    unsigned aofs[2], bofs[2];
    #pragma unroll
    for (int s = 0; s < 2; s++) {
        int r = w * 32 + s * 16 + (l >> 2);
        aofs[s] = (unsigned)tok_s[r] * HD + (unsigned)((l & 3) * 8);
        bofs[s] = (unsigned)(r * HD) + (unsigned)((l & 3) * 8);
    }

    floatx4 acc[4][4];
    #pragma unroll
    for (int i = 0; i < 4; i++)
        #pragma unroll
        for (int j = 0; j < 4; j++) acc[i][j] = (floatx4){0.f, 0.f, 0.f, 0.f};

    // prologue DMA -> buf 0 (k=0), buf 1 (k=32)
    #pragma unroll
    for (int p = 0; p < 2; p++)
        #pragma unroll
        for (int s = 0; s < 2; s++) {
            gload16(xb  + aofs[s] + p * BK, &smem[p][0][(w * 32 + s * 16) * BK]);
            gload16(w1e + bofs[s] + p * BK, &smem[p][1][(w * 32 + s * 16) * BK]);
        }

    const int NIT = HD / BK;                   // 16
    int rb = 0;
    for (int k = 0; k < NIT; ++k) {
        if (k + 1 < NIT) asm volatile("s_waitcnt vmcnt(4)" ::: "memory");
        else             asm volatile("s_waitcnt vmcnt(0)" ::: "memory");
        __builtin_amdgcn_s_barrier();
        asm volatile("" ::: "memory");         // keep DMA/ds_read after the barrier
        if (k + 2 < NIT) {
            int ib = (rb == 0) ? 2 : rb - 1;   // (rb+2)%3: buffer read at iter k-1
            int ko = (k + 2) * BK;
            #pragma unroll
            for (int s = 0; s < 2; s++) {
                gload16(xb  + aofs[s] + ko, &smem[ib][0][(w * 32 + s * 16) * BK]);
                gload16(w1e + bofs[s] + ko, &smem[ib][1][(w * 32 + s * 16) * BK]);
            }
        }
        const unsigned short* A = smem[rb][0];
        const unsigned short* B = smem[rb][1];
        bf16x8 a[4], b[4];
        #pragma unroll
        for (int i = 0; i < 4; i++) a[i] = *(const bf16x8*)&A[(wm + 16 * i + lr) * BK + kq];
        #pragma unroll
        for (int j = 0; j < 4; j++) b[j] = *(const bf16x8*)&B[(wn + 16 * j + lr) * BK + kq];
        __builtin_amdgcn_s_setprio(1);
        #pragma unroll
        for (int i = 0; i < 4; i++)
            #pragma unroll
            for (int j = 0; j < 4; j++)
                acc[i][j] = __builtin_amdgcn_mfma_f32_16x16x32_bf16(a[i], b[j], acc[i][j], 0, 0, 0);
        __builtin_amdgcn_s_setprio(0);
        rb = (rb == 2) ? 0 : rb + 1;
    }
    __syncthreads();                           // done with buffers before scratch reuse

    // epilogue: +b1, gelu, bf16 -> per-wave LDS scratch (LD 72) -> coalesced 16B stores
    unsigned short* scr = &smem[0][0][0] + w * 64 * 72;
    #pragma unroll
    for (int j = 0; j < 4; j++) {
        float b1v = bias1[e * DFF + nb * TN + wn + 16 * j + lr];
        #pragma unroll
        for (int i = 0; i < 4; i++)
            #pragma unroll
            for (int rr = 0; rr < 4; rr++)
                scr[(16 * i + crow + rr) * 72 + 16 * j + lr] = f2bf(gelu_exact(acc[i][j][rr] + b1v));
    }
    __syncthreads();
    int lh = l >> 3, ll = l & 7;
    #pragma unroll
    for (int k = 0; k < 8; k++) {
        uint4 v = *(const uint4*)&scr[(8 * k + lh) * 72 + ll * 8];
        int grow = hb + wm + 8 * k + lh;
        *(uint4*)&hbuf[(size_t)grow * DFF + nb * TN + wn + ll * 8] = v;
    }
}

// GEMM2: out[seg_token[e][row], n] += seg_w[e][row] * ( hbuf[row, :] @ W2t[e][n, :] + b2[e][n] )
__global__ __launch_bounds__(256) void gemm2_kernel(
    const unsigned short* __restrict__ hbuf,
    const unsigned short* __restrict__ W2t,   // [E][HD][DFF] n-major
    const float* __restrict__ b2,
    const int* __restrict__ seg_count, const int* __restrict__ seg_token,
    const float* __restrict__ seg_w,
    float* __restrict__ out)
{
    int bid = blockIdx.x;
    int tid = threadIdx.x;
    int e  = bid & 7;
    int r2 = bid >> 3;
    int nb = r2 & 3;                           // HD/TN = 4
    int mb = r2 >> 2;                          // 0..63
    int cnt = seg_count[e];
    if (mb * TM >= cnt) return;
    int off_e = 0;
    #pragma unroll
    for (int ee = 0; ee < NE; ee++) if (ee < e) off_e += (seg_count[ee] + 127) & ~127;
    int hb = off_e + mb * TM;

    __shared__ __align__(16) unsigned short smem[3][2][TM * BK];   // 49152 B
    __shared__ int   tok_s[TM];
    __shared__ float wgt_s[TM];
    if (tid < TM) {
        int gi = mb * TM + tid;
        tok_s[tid] = seg_token[e * TOK + ((gi < cnt) ? gi : 0)];
        wgt_s[tid] = (gi < cnt) ? seg_w[e * TOK + gi] : 0.f;      // pad weight 0
    }
    __syncthreads();

    int w = tid >> 6, l = tid & 63;
    int lr = l & 15, crow = (l >> 4) * 4;
    int wm = (w & 1) * 64, wn = (w >> 1) * 64;
    int kq = (l >> 4) * 8;
    const unsigned short* w2e = W2t + (size_t)e * HD * DFF + (size_t)(nb * TN) * DFF;

    unsigned aofs[2], bofs[2];
    #pragma unroll
    for (int s = 0; s < 2; s++) {
        int r = w * 32 + s * 16 + (l >> 2);
        aofs[s] = (unsigned)((hb + r) * DFF) + (unsigned)((l & 3) * 8);
        bofs[s] = (unsigned)(r * DFF) + (unsigned)((l & 3) * 8);
    }

    floatx4 acc[4][4];
    #pragma unroll
    for (int i = 0; i < 4; i++)
        #pragma unroll
        for (int j = 0; j < 4; j++) acc[i][j] = (floatx4){0.f, 0.f, 0.f, 0.f};

    #pragma unroll
    for (int p = 0; p < 2; p++)
        #pragma unroll
        for (int s = 0; s < 2; s++) {
            gload16(hbuf + aofs[s] + p * BK, &smem[p][0][(w * 32 + s * 16) * BK]);
            gload16(w2e  + bofs[s] + p * BK, &smem[p][1][(w * 32 + s * 16) * BK]);
        }

    const int NIT = DFF / BK;                  // 64
    int rb = 0;
    for (int k = 0; k < NIT; ++k) {
        if (k + 1 < NIT) asm volatile("s_waitcnt vmcnt(4)" ::: "memory");
        else             asm volatile("s_waitcnt vmcnt(0)" ::: "memory");
        __builtin_amdgcn_s_barrier();
        asm volatile("" ::: "memory");
        if (k + 2 < NIT) {
            int ib = (rb == 0) ? 2 : rb - 1;
            int ko = (k + 2) * BK;
            #pragma unroll
            for (int s = 0; s < 2; s++) {
                gload16(hbuf + aofs[s] + ko, &smem[ib][0][(w * 32 + s * 16) * BK]);
                gload16(w2e  + bofs[s] + ko, &smem[ib][1][(w * 32 + s * 16) * BK]);
            }
        }
        const unsigned short* A = smem[rb][0];
        const unsigned short* B = smem[rb][1];
        bf16x8 a[4], b[4];
        #pragma unroll
        for (int i = 0; i < 4; i++) a[i] = *(const bf16x8*)&A[(wm + 16 * i + lr) * BK + kq];
        #pragma unroll
        for (int j = 0; j < 4; j++) b[j] = *(const bf16x8*)&B[(wn + 16 * j + lr) * BK + kq];
        __builtin_amdgcn_s_setprio(1);
        #pragma unroll
        for (int i = 0; i < 4; i++)
            #pragma unroll
            for (int j = 0; j < 4; j++)
                acc[i][j] = __builtin_amdgcn_mfma_f32_16x16x32_bf16(a[i], b[j], acc[i][j], 0, 0, 0);
        __builtin_amdgcn_s_setprio(0);
        rb = (rb == 2) ? 0 : rb + 1;
    }

    // epilogue: +b2, x gate weight, atomicAdd (2 adds/element total across experts)
    #pragma unroll
    for (int j = 0; j < 4; j++) {
        int n = nb * TN + wn + 16 * j + lr;
        float b2v = b2[e * HD + n];
        #pragma unroll
        for (int i = 0; i < 4; i++)
            #pragma unroll
            for (int rr = 0; rr < 4; rr++) {
                int m = wm + 16 * i + crow + rr;
                atomicAdd(&out[(size_t)tok_s[m] * HD + n], (acc[i][j][rr] + b2v) * wgt_s[m]);
            }
    }
}

// ---------------- fused fallback (ws too small): R2-style, swizzled ----------------
#define BMT 64
#define FK  64
#define XS_LD 520
#define HS_LD 72

__global__ __launch_bounds__(256, 2) void ffn_fused_fallback(
    const unsigned short* __restrict__ xb,
    const unsigned short* __restrict__ W1t, const float* __restrict__ b1,
    const unsigned short* __restrict__ W2t, const float* __restrict__ b2,
    const int* __restrict__ seg_count, const int* __restrict__ seg_token,
    const float* __restrict__ seg_w, float* __restrict__ out)
{
    int bid = blockIdx.x;
    int e = bid & 7;
    int g = bid >> 3;
    int cnt = seg_count[e];
    int n0 = g * BMT;
    if (n0 >= cnt) return;
    int rows = min(BMT, cnt - n0);

    __shared__ unsigned short xs[BMT * XS_LD];
    __shared__ unsigned short hs[BMT * HS_LD];
    __shared__ int   tok_s[BMT];
    __shared__ float wgt_s[BMT];

    int tid = threadIdx.x;
    if (tid < BMT) {
        int idx = (tid < rows) ? (n0 + tid) : n0;
        tok_s[tid] = seg_token[e * TOK + idx];
        wgt_s[tid] = (tid < rows) ? seg_w[e * TOK + idx] : 0.f;
    }
    __syncthreads();
    {
        int r = tid >> 2, q = tid & 3;
        const uint4* src = (const uint4*)(xb + (size_t)tok_s[r] * HD) + q * 16;
        uint4* dst = (uint4*)&xs[(size_t)r * XS_LD + q * 128];
        #pragma unroll
        for (int i = 0; i < 16; i++) dst[i] = src[i];
    }
    __syncthreads();

    int w = tid >> 6, l = tid & 63;
    int lr = l & 15, lk = (l >> 4) * 8, crow = (l >> 4) * 4;

    const unsigned short* w1e = W1t + (size_t)e * DFF * HD;
    const unsigned short* w2e = W2t + (size_t)e * HD * DFF;

    floatx4 acc2[4][8];
    #pragma unroll
    for (int i = 0; i < 4; i++)
        #pragma unroll
        for (int j = 0; j < 8; j++) acc2[i][j] = (floatx4){0.f, 0.f, 0.f, 0.f};

    for (int fc = 0; fc < DFF; fc += FK) {
        floatx4 acc1[4];
        #pragma unroll
        for (int t = 0; t < 4; t++) acc1[t] = (floatx4){0.f, 0.f, 0.f, 0.f};
        const unsigned short* w1c = w1e + (size_t)fc * HD;
        for (int ks = 0; ks < HD; ks += 32) {
            bf16x8 a = *(const bf16x8*)&xs[(16 * w + lr) * XS_LD + ks + lk];
            #pragma unroll
            for (int t = 0; t < 4; t++) {
                bf16x8 b = *(const bf16x8*)(w1c + (size_t)(16 * t + lr) * HD + ks + lk);
                acc1[t] = __builtin_amdgcn_mfma_f32_16x16x32_bf16(a, b, acc1[t], 0, 0, 0);
            }
        }
        __syncthreads();
        #pragma unroll
        for (int t = 0; t < 4; t++) {
            float b1v = b1[e * DFF + fc + 16 * t + lr];
            #pragma unroll
            for (int r = 0; r < 4; r++)
                hs[(16 * w + crow + r) * HS_LD + 16 * t + lr] = f2bf(gelu_exact(acc1[t][r] + b1v));
        }
        __syncthreads();
        #pragma unroll
        for (int ks = 0; ks < FK; ks += 32) {
            bf16x8 af[4];
            #pragma unroll
            for (int i = 0; i < 4; i++) af[i] = *(const bf16x8*)&hs[(16 * i + lr) * HS_LD + ks + lk];
            #pragma unroll 4
            for (int j = 0; j < 8; j++) {
                bf16x8 b = *(const bf16x8*)(w2e + (size_t)(128 * w + 16 * j + lr) * DFF + fc + ks + lk);
                #pragma unroll
                for (int i = 0; i < 4; i++)
                    acc2[i][j] = __builtin_amdgcn_mfma_f32_16x16x32_bf16(af[i], b, acc2[i][j], 0, 0, 0);
            }
        }
    }
    #pragma unroll
    for (int j = 0; j < 8; j++) {
        int n = 128 * w + 16 * j + lr;
        float b2v = b2[e * HD + n];
        #pragma unroll
        for (int i = 0; i < 4; i++)
            #pragma unroll
            for (int r = 0; r < 4; r++) {
                int m = 16 * i + crow + r;
                atomicAdd(&out[(size_t)tok_s[m] * HD + n], (acc2[i][j][r] + b2v) * wgt_s[m]);
            }
    }
}

// tiny finalize for fallback path
__global__ void finalize_kernel(const int* __restrict__ seg_count,
                                const float* __restrict__ probs_sum,
                                float* __restrict__ out_tail)
{
    int tid = threadIdx.x;
    if (tid < NE) out_tail[1 + tid] = (float)seg_count[tid];
    if (tid == 0) {
        float s = 0.f;
        #pragma unroll
        for (int e = 0; e < NE; e++) {
            float p = probs_sum[e] * (1.f / (float)TOK);
            s += p * p;
        }
        out_tail[0] = s * (float)NE;
    }
}

extern "C" void kernel_launch(void* const* d_in, const int* in_sizes, int n_in,
                              void* d_out, int out_size, void* d_ws, size_t ws_size,
                              hipStream_t stream)
{
    const float* x  = (const float*)d_in[0];
    const float* gW = (const float*)d_in[1];
    const float* gb = (const float*)d_in[2];
    const float* W1 = (const float*)d_in[3];
    const float* b1 = (const float*)d_in[4];
    const float* W2 = (const float*)d_in[5];
    const float* b2 = (const float*)d_in[6];
    float* out = (float*)d_out;

    // workspace layout (bytes)
    char* ws = (char*)d_ws;
    int*   seg_count = (int*)ws;                          // 32 B
    float* probs_sum = (float*)(ws + 32);                 // 32 B
    int*   seg_token = (int*)(ws + 262144);               // NE*TOK*4
    float* seg_w     = (float*)(ws + 262144 + (size_t)NE * TOK * 4);
    unsigned short* xb   = (unsigned short*)(ws + (1u  << 20));  //  8 MiB
    unsigned short* W1t  = (unsigned short*)(ws + (16u << 20));  // 16 MiB
    unsigned short* W2t  = (unsigned short*)(ws + (32u << 20));  // 16 MiB
    unsigned short* hbuf = (unsigned short*)(ws + (48u << 20));  // up to 71.3 MB

    const size_t WS_SPLIT = (size_t)(48u << 20) + (size_t)17408 * DFF * 2;  // ~122 MB

    hipMemsetAsync(d_ws, 0, 64, stream);
    hipMemsetAsync(d_out, 0, (size_t)TOK * HD * sizeof(float), stream);

    // gate (32 blocks) + weight transpose (4096 blocks), fused
    prep_kernel<<<4128, 256, 0, stream>>>(x, gW, gb, W1, W2,
                                          seg_count, probs_sum, seg_token, seg_w,
                                          xb, W1t, W2t);

    if (ws_size >= WS_SPLIT) {
        gemm1_kernel<<<NE * (DFF / TN) * 64, 256, 0, stream>>>(
            xb, W1t, b1, seg_count, probs_sum, seg_token, hbuf,
            out + (size_t)TOK * HD);
        gemm2_kernel<<<NE * (HD / TN) * 64, 256, 0, stream>>>(
            hbuf, W2t, b2, seg_count, seg_token, seg_w, out);
    } else {
        finalize_kernel<<<1, 64, 0, stream>>>(seg_count, probs_sum, out + (size_t)TOK * HD);
        ffn_fused_fallback<<<(TOK / BMT) * NE, 256, 0, stream>>>(
            xb, W1t, b1, W2t, b2, seg_count, seg_token, seg_w, out);
    }
}